// Round 1
// baseline (2850.993 us; speedup 1.0000x reference)
//
#include <hip/hip_runtime.h>

// Problem constants (fixed by the reference): B=4, C=256, C8=32, N=H*W=4096.
#define BB 4
#define CC 256
#define C8 32
#define NN 4096

// ---------------------------------------------------------------------------
// Projection: out[b,o,n] = bias[o] + sum_c W[o,c] * in[b,c,n]
// grid (NN/64, BB), block 256. Thread: n = t&63 (lane), o_slot = t>>6 (wave id,
// wave-uniform -> W/bias loads become scalar loads through the constant cache).
// Register tile OT outputs per thread: 1 LDS read amortized over OT FMAs.
// ---------------------------------------------------------------------------
template<int O, int OT>
__global__ __launch_bounds__(256)
void proj_kernel(const float* __restrict__ in, const float* __restrict__ W,
                 const float* __restrict__ bias, float* __restrict__ out)
{
    __shared__ float x_lds[CC][64];   // 64 KB (static max) — input tile
    const int b  = blockIdx.y;
    const int n0 = blockIdx.x * 64;
    const int t  = threadIdx.x;
    const float* inb = in + (size_t)b * CC * NN + n0;

    for (int idx = t; idx < CC * 64; idx += 256) {
        int c = idx >> 6, n = idx & 63;
        x_lds[c][n] = inb[c * NN + n];          // coalesced 256B rows
    }
    __syncthreads();

    const int n      = t & 63;
    const int o_slot = __builtin_amdgcn_readfirstlane(t >> 6);  // wave-uniform
    float* outb = out + (size_t)b * O * NN + n0;

    for (int ob = o_slot * OT; ob < O; ob += 4 * OT) {
        float acc[OT];
        #pragma unroll
        for (int j = 0; j < OT; ++j) acc[j] = bias[ob + j];
        for (int c = 0; c < CC; ++c) {
            float xv = x_lds[c][n];             // bank = n, conflict-free
            #pragma unroll
            for (int j = 0; j < OT; ++j)
                acc[j] = fmaf(W[(ob + j) * CC + c], xv, acc[j]);  // scalar load
        }
        #pragma unroll
        for (int j = 0; j < OT; ++j)
            outb[(ob + j) * NN + n] = acc[j];   // coalesced
    }
}

// ---------------------------------------------------------------------------
// Stats pass: S[n,m] = sum_c f[c,n]*g[c,m] (c < 32); output M[n] = max_m S,
// Linv[n] = 1/sum_m exp(S - M).  grid (NN/64, BB), block 256.
// Thread: pair = t&31 handles n = n0+2*pair+{0,1} (f cached in 64 regs);
// m_slot = t>>5 handles 8 contiguous m per 64-tile -> g read as float4 (b128).
// ---------------------------------------------------------------------------
__global__ __launch_bounds__(256)
void stats_kernel(const float* __restrict__ f, const float* __restrict__ g,
                  float* __restrict__ Mout, float* __restrict__ Linv)
{
    __shared__ float f_lds[C8][64];                      // 8 KB
    __shared__ __align__(16) float g_lds[C8][68];        // pad 68: b128-aligned rows
    __shared__ float red_m[8][64];
    __shared__ float red_l[8][64];

    const int b  = blockIdx.y;
    const int n0 = blockIdx.x * 64;
    const int t  = threadIdx.x;
    const float* fb = f + (size_t)b * C8 * NN;
    const float* gb = g + (size_t)b * C8 * NN;

    for (int idx = t; idx < C8 * 64; idx += 256) {
        int c = idx >> 6, n = idx & 63;
        f_lds[c][n] = fb[c * NN + n0 + n];
    }
    __syncthreads();

    const int pair   = t & 31;
    const int m_slot = t >> 5;      // 0..7
    float fr0[C8], fr1[C8];
    #pragma unroll
    for (int c = 0; c < C8; ++c) {
        fr0[c] = f_lds[c][pair * 2 + 0];
        fr1[c] = f_lds[c][pair * 2 + 1];
    }
    float m0 = -1e30f, l0 = 0.0f, m1 = -1e30f, l1 = 0.0f;

    for (int mt = 0; mt < NN; mt += 64) {
        __syncthreads();                         // protect g_lds reuse
        for (int idx = t; idx < C8 * 64; idx += 256) {
            int c = idx >> 6, mm = idx & 63;
            g_lds[c][mm] = gb[c * NN + mt + mm];
        }
        __syncthreads();

        float s0[8], s1[8];
        #pragma unroll
        for (int k = 0; k < 8; ++k) { s0[k] = 0.0f; s1[k] = 0.0f; }
        #pragma unroll
        for (int c = 0; c < C8; ++c) {
            float4 ga = *(const float4*)&g_lds[c][m_slot * 8 + 0];
            float4 gc = *(const float4*)&g_lds[c][m_slot * 8 + 4];
            float f0 = fr0[c], f1 = fr1[c];
            s0[0] = fmaf(ga.x, f0, s0[0]); s0[1] = fmaf(ga.y, f0, s0[1]);
            s0[2] = fmaf(ga.z, f0, s0[2]); s0[3] = fmaf(ga.w, f0, s0[3]);
            s0[4] = fmaf(gc.x, f0, s0[4]); s0[5] = fmaf(gc.y, f0, s0[5]);
            s0[6] = fmaf(gc.z, f0, s0[6]); s0[7] = fmaf(gc.w, f0, s0[7]);
            s1[0] = fmaf(ga.x, f1, s1[0]); s1[1] = fmaf(ga.y, f1, s1[1]);
            s1[2] = fmaf(ga.z, f1, s1[2]); s1[3] = fmaf(ga.w, f1, s1[3]);
            s1[4] = fmaf(gc.x, f1, s1[4]); s1[5] = fmaf(gc.y, f1, s1[5]);
            s1[6] = fmaf(gc.z, f1, s1[6]); s1[7] = fmaf(gc.w, f1, s1[7]);
        }
        #pragma unroll
        for (int k = 0; k < 8; ++k) {
            // online max/sum-exp (branch rarely taken after warm-up)
            if (s0[k] > m0) { l0 = l0 * __expf(m0 - s0[k]) + 1.0f; m0 = s0[k]; }
            else            { l0 += __expf(s0[k] - m0); }
            if (s1[k] > m1) { l1 = l1 * __expf(m1 - s1[k]) + 1.0f; m1 = s1[k]; }
            else            { l1 += __expf(s1[k] - m1); }
        }
    }

    red_m[m_slot][pair * 2 + 0] = m0;  red_l[m_slot][pair * 2 + 0] = l0;
    red_m[m_slot][pair * 2 + 1] = m1;  red_l[m_slot][pair * 2 + 1] = l1;
    __syncthreads();
    if (t < 64) {
        float M = -1e30f;
        #pragma unroll
        for (int s = 0; s < 8; ++s) M = fmaxf(M, red_m[s][t]);
        float L = 0.0f;
        #pragma unroll
        for (int s = 0; s < 8; ++s) L = fmaf(red_l[s][t], __expf(red_m[s][t] - M), L);
        Mout[(size_t)b * NN + n0 + t] = M;
        Linv[(size_t)b * NN + n0 + t] = 1.0f / L;
    }
}

// ---------------------------------------------------------------------------
// PV pass: out[b,c,m] = src[b,c,m] + gamma * sum_n h[c,n]*exp(S[n,m]-M[n])*Linv[n]
// grid (NN/64, BB), block 256. Per 32-n tile:
//   phase A: thread (m = t&63, wave w = t>>6) computes S[n,m] for n = 8w..8w+7
//            (f via b128 broadcast reads, g cached in 32 regs), writes P to LDS.
//   phase B: thread (c_grp = t>>3, m_grp = t&7) does 8c x 8m outer product,
//            h/P read as b128 along n (stride-36 pad: aligned + conflict-free).
// ---------------------------------------------------------------------------
__global__ __launch_bounds__(256)
void pv_kernel(const float* __restrict__ f, const float* __restrict__ g,
               const float* __restrict__ h,
               const float* __restrict__ Mbuf, const float* __restrict__ Linv,
               const float* __restrict__ src, const float* __restrict__ gamma,
               float* __restrict__ out)
{
    __shared__ __align__(16) float f_lds[C8][36];   // 4.5 KB
    __shared__ __align__(16) float P_lds[64][36];   // 9 KB
    __shared__ __align__(16) float h_lds[CC][36];   // 36 KB
    __shared__ float M_s[32], Li_s[32];

    const int b  = blockIdx.y;
    const int m0 = blockIdx.x * 64;
    const int t  = threadIdx.x;
    const float* fb = f + (size_t)b * C8 * NN;
    const float* gb = g + (size_t)b * C8 * NN;
    const float* hb = h + (size_t)b * CC * NN;

    const int m_lane = t & 63;
    const int n_base = t >> 6;        // wave id 0..3
    float greg[C8];
    #pragma unroll
    for (int c = 0; c < C8; ++c) greg[c] = gb[c * NN + m0 + m_lane];  // coalesced

    const int c_grp = t >> 3;         // 0..31 -> c = c_grp + 32j
    const int m_grp = t & 7;          // 0..7  -> m = m_grp + 8k
    float acc[8][8];
    #pragma unroll
    for (int j = 0; j < 8; ++j)
        #pragma unroll
        for (int k = 0; k < 8; ++k) acc[j][k] = 0.0f;

    for (int nt = 0; nt < NN; nt += 32) {
        __syncthreads();              // previous phase B done before restaging
        for (int idx = t; idx < C8 * 32; idx += 256) {
            int c = idx >> 5, n = idx & 31;
            f_lds[c][n] = fb[c * NN + nt + n];
        }
        for (int idx = t; idx < CC * 32; idx += 256) {
            int c = idx >> 5, n = idx & 31;
            h_lds[c][n] = hb[c * NN + nt + n];   // write bank (4c+n): free
        }
        if (t < 32) {
            M_s[t]  = Mbuf[(size_t)b * NN + nt + t];
            Li_s[t] = Linv[(size_t)b * NN + nt + t];
        }
        __syncthreads();

        // ---- phase A: S + P for this thread's column m, rows 8*n_base..+7
        {
            float sacc[8];
            #pragma unroll
            for (int k = 0; k < 8; ++k) sacc[k] = 0.0f;
            #pragma unroll
            for (int c = 0; c < C8; ++c) {
                float4 fa = *(const float4*)&f_lds[c][n_base * 8 + 0];
                float4 fc = *(const float4*)&f_lds[c][n_base * 8 + 4];
                float gv = greg[c];
                sacc[0] = fmaf(fa.x, gv, sacc[0]); sacc[1] = fmaf(fa.y, gv, sacc[1]);
                sacc[2] = fmaf(fa.z, gv, sacc[2]); sacc[3] = fmaf(fa.w, gv, sacc[3]);
                sacc[4] = fmaf(fc.x, gv, sacc[4]); sacc[5] = fmaf(fc.y, gv, sacc[5]);
                sacc[6] = fmaf(fc.z, gv, sacc[6]); sacc[7] = fmaf(fc.w, gv, sacc[7]);
            }
            #pragma unroll
            for (int k = 0; k < 8; ++k) {
                int n = n_base * 8 + k;
                P_lds[m_lane][n] = __expf(sacc[k] - M_s[n]) * Li_s[n];
            }
        }
        __syncthreads();

        // ---- phase B: acc[c,m] += h[c,n]*P[m,n], b128 along n
        for (int n4 = 0; n4 < 32; n4 += 4) {
            float4 pq[8];
            #pragma unroll
            for (int k = 0; k < 8; ++k)
                pq[k] = *(const float4*)&P_lds[m_grp + 8 * k][n4];
            #pragma unroll
            for (int j = 0; j < 8; ++j) {
                float4 hq = *(const float4*)&h_lds[c_grp + 32 * j][n4];
                #pragma unroll
                for (int k = 0; k < 8; ++k) {
                    acc[j][k] = fmaf(hq.x, pq[k].x, acc[j][k]);
                    acc[j][k] = fmaf(hq.y, pq[k].y, acc[j][k]);
                    acc[j][k] = fmaf(hq.z, pq[k].z, acc[j][k]);
                    acc[j][k] = fmaf(hq.w, pq[k].w, acc[j][k]);
                }
            }
        }
    }

    // ---- epilogue: out = src + gamma * acc
    const float gm = gamma[0];
    const float* srcb = src + (size_t)b * CC * NN;
    float* outb = out + (size_t)b * CC * NN;
    #pragma unroll
    for (int j = 0; j < 8; ++j) {
        int c = c_grp + 32 * j;
        #pragma unroll
        for (int k = 0; k < 8; ++k) {
            int m = m0 + m_grp + 8 * k;
            outb[(size_t)c * NN + m] = fmaf(gm, acc[j][k], srcb[(size_t)c * NN + m]);
        }
    }
}

// ---------------------------------------------------------------------------
extern "C" void kernel_launch(void* const* d_in, const int* in_sizes, int n_in,
                              void* d_out, int out_size, void* d_ws, size_t ws_size,
                              hipStream_t stream)
{
    const float* x    = (const float*)d_in[0];
    const float* y    = (const float*)d_in[1];
    const float* Wfx  = (const float*)d_in[2];
    const float* bfx  = (const float*)d_in[3];
    const float* Wgx  = (const float*)d_in[4];
    const float* bgx  = (const float*)d_in[5];
    const float* Whx  = (const float*)d_in[6];
    const float* bhx  = (const float*)d_in[7];
    const float* Wfy  = (const float*)d_in[8];
    const float* bfy  = (const float*)d_in[9];
    const float* Wgy  = (const float*)d_in[10];
    const float* bgy  = (const float*)d_in[11];
    const float* Why  = (const float*)d_in[12];
    const float* bhy  = (const float*)d_in[13];
    const float* gam  = (const float*)d_in[14];

    // workspace layout (floats): fx gx fy gy hx hy Mx Lx My Ly  (~42.2 MB)
    float* ws = (float*)d_ws;
    const size_t SZ_FG = (size_t)BB * C8 * NN;   // 524288
    const size_t SZ_H  = (size_t)BB * CC * NN;   // 4194304
    const size_t SZ_ML = (size_t)BB * NN;        // 16384
    float* fx = ws;
    float* gx = fx + SZ_FG;
    float* fy = gx + SZ_FG;
    float* gy = fy + SZ_FG;
    float* hx = gy + SZ_FG;
    float* hy = hx + SZ_H;
    float* Mx = hy + SZ_H;
    float* Lx = Mx + SZ_ML;
    float* My = Lx + SZ_ML;
    float* Ly = My + SZ_ML;

    float* outx = (float*)d_out;
    float* outy = outx + SZ_H;

    dim3 grid(NN / 64, BB);

    // projections
    proj_kernel<32, 8 ><<<grid, 256, 0, stream>>>(x, Wfx, bfx, fx);
    proj_kernel<32, 8 ><<<grid, 256, 0, stream>>>(x, Wgx, bgx, gx);
    proj_kernel<256,16><<<grid, 256, 0, stream>>>(x, Whx, bhx, hx);
    proj_kernel<32, 8 ><<<grid, 256, 0, stream>>>(y, Wfy, bfy, fy);
    proj_kernel<32, 8 ><<<grid, 256, 0, stream>>>(y, Wgy, bgy, gy);
    proj_kernel<256,16><<<grid, 256, 0, stream>>>(y, Why, bhy, hy);

    // softmax row stats: att_x rows come from fy (vs gx); att_y rows from fx (vs gy)
    stats_kernel<<<grid, 256, 0, stream>>>(fy, gx, Mx, Lx);
    stats_kernel<<<grid, 256, 0, stream>>>(fx, gy, My, Ly);

    // PV + residual epilogue
    pv_kernel<<<grid, 256, 0, stream>>>(fy, gx, hx, Mx, Lx, x, gam, outx);
    pv_kernel<<<grid, 256, 0, stream>>>(fx, gy, hy, My, Ly, y, gam, outy);
}

// Round 2
// 721.510 us; speedup vs baseline: 3.9514x; 3.9514x over previous
//
#include <hip/hip_runtime.h>

// B=4, C=256, C8=32, N=4096. fp16 MFMA (16x16x32) for S and PV GEMMs.
#define BB 4
#define CC 256
#define NN 4096

typedef _Float16 half_t;
typedef __attribute__((ext_vector_type(8))) _Float16 half8;
typedef __attribute__((ext_vector_type(4))) _Float16 half4;
typedef __attribute__((ext_vector_type(4))) float floatx4;

// ---------------------------------------------------------------------------
// proj_fg: O=32. out fT[n][32] fp16 (transposed -> MFMA A/B frags contiguous).
// grid (64, 4), block 256. Compute in fp32 (W stays fp32), cast on store.
// ---------------------------------------------------------------------------
__global__ __launch_bounds__(256)
void proj_fg_kernel(const float* __restrict__ in, const float* __restrict__ W,
                    const float* __restrict__ bias, half_t* __restrict__ outT)
{
    __shared__ float x_lds[CC][64];
    const int b  = blockIdx.y;
    const int n0 = blockIdx.x * 64;
    const int t  = threadIdx.x;
    const float* inb = in + (size_t)b * CC * NN + n0;

    // stage: 256 rows x 16 float4 chunks = 4096 / 256 threads = 16 iters
    for (int i = 0; i < 16; ++i) {
        int idx = t + 256 * i, row = idx >> 4, ch = idx & 15;
        *(float4*)&x_lds[row][ch * 4] = *(const float4*)&inb[(size_t)row * NN + ch * 4];
    }
    __syncthreads();

    const int n      = t & 63;
    const int o_slot = __builtin_amdgcn_readfirstlane(t >> 6);  // wave-uniform
    const int ob     = o_slot * 8;
    float acc[8];
    #pragma unroll
    for (int j = 0; j < 8; ++j) acc[j] = bias[ob + j];
    for (int c = 0; c < CC; ++c) {
        float xv = x_lds[c][n];
        #pragma unroll
        for (int j = 0; j < 8; ++j)
            acc[j] = fmaf(W[(ob + j) * CC + c], xv, acc[j]);  // scalar (uniform) loads
    }
    half8 hv;
    #pragma unroll
    for (int j = 0; j < 8; ++j) hv[j] = (half_t)acc[j];
    *(half8*)&outT[((size_t)b * NN + n0 + n) * 32 + ob] = hv;   // 16B store
}

// ---------------------------------------------------------------------------
// proj_h: O=256. out h[c][n] fp16 (natural layout = PV A-operand layout).
// grid (64, 4), block 256.
// ---------------------------------------------------------------------------
__global__ __launch_bounds__(256)
void proj_h_kernel(const float* __restrict__ in, const float* __restrict__ W,
                   const float* __restrict__ bias, half_t* __restrict__ out)
{
    __shared__ float x_lds[CC][64];
    const int b  = blockIdx.y;
    const int n0 = blockIdx.x * 64;
    const int t  = threadIdx.x;
    const float* inb = in + (size_t)b * CC * NN + n0;

    for (int i = 0; i < 16; ++i) {
        int idx = t + 256 * i, row = idx >> 4, ch = idx & 15;
        *(float4*)&x_lds[row][ch * 4] = *(const float4*)&inb[(size_t)row * NN + ch * 4];
    }
    __syncthreads();

    const int n      = t & 63;
    const int o_slot = __builtin_amdgcn_readfirstlane(t >> 6);
    half_t* outb = out + (size_t)b * CC * NN + n0;

    for (int ob = o_slot * 16; ob < CC; ob += 64) {
        float acc[16];
        #pragma unroll
        for (int j = 0; j < 16; ++j) acc[j] = bias[ob + j];
        for (int c = 0; c < CC; ++c) {
            float xv = x_lds[c][n];
            #pragma unroll
            for (int j = 0; j < 16; ++j)
                acc[j] = fmaf(W[(ob + j) * CC + c], xv, acc[j]);
        }
        #pragma unroll
        for (int j = 0; j < 16; ++j)
            outb[(size_t)(ob + j) * NN + n] = (half_t)acc[j];   // coalesced u16
    }
}

// ---------------------------------------------------------------------------
// stats: M[n] = max_m S[n,m], Linv[n] = 1/sum_m exp(S-M); S = fT . gT^T via MFMA.
// grid (128, 4) -> 32-n tile per block, block 256 (4 waves split the m range).
// ---------------------------------------------------------------------------
__global__ __launch_bounds__(256)
void stats_kernel(const half_t* __restrict__ fT, const half_t* __restrict__ gT,
                  float* __restrict__ Mout, float* __restrict__ Linv)
{
    __shared__ half_t f_lds[32][40];     // pitch 40: uniform quad-bank spread
    __shared__ half_t g_lds[256][40];
    __shared__ float red_m[4][32], red_l[4][32];

    const int b  = blockIdx.y;
    const int n0 = blockIdx.x * 32;
    const int t  = threadIdx.x;
    const half_t* fTb = fT + (size_t)b * NN * 32;
    const half_t* gTb = gT + (size_t)b * NN * 32;

    if (t < 128) {   // 32 rows x 4 chunks
        int row = t >> 2, ch = t & 3;
        *(half8*)&f_lds[row][ch * 8] = *(const half8*)&fTb[(size_t)(n0 + row) * 32 + ch * 8];
    }
    __syncthreads();

    const int w = t >> 6, lane = t & 63, q = lane >> 4, mc = lane & 15;
    half8 afr[2];
    afr[0] = *(const half8*)&f_lds[mc][q * 8];        // A: row n=mc, k=q*8..+8
    afr[1] = *(const half8*)&f_lds[16 + mc][q * 8];

    float m_run[2][4], l_run[2][4];
    #pragma unroll
    for (int s = 0; s < 2; ++s)
        #pragma unroll
        for (int r = 0; r < 4; ++r) { m_run[s][r] = -1e30f; l_run[s][r] = 0.0f; }

    for (int mt = 0; mt < NN; mt += 256) {
        __syncthreads();
        #pragma unroll
        for (int i = 0; i < 4; ++i) {    // 256 rows x 4 chunks = 1024
            int idx = t + 256 * i, row = idx >> 2, ch = idx & 3;
            *(half8*)&g_lds[row][ch * 8] = *(const half8*)&gTb[(size_t)(mt + row) * 32 + ch * 8];
        }
        __syncthreads();

        #pragma unroll
        for (int ms = 0; ms < 4; ++ms) {
            half8 bfr = *(const half8*)&g_lds[w * 64 + ms * 16 + mc][q * 8];
            #pragma unroll
            for (int s = 0; s < 2; ++s) {
                floatx4 S = __builtin_amdgcn_mfma_f32_16x16x32_f16(
                    afr[s], bfr, (floatx4){0.f, 0.f, 0.f, 0.f}, 0, 0, 0);
                #pragma unroll
                for (int r = 0; r < 4; ++r) {
                    float sv = S[r];
                    float mn = fmaxf(m_run[s][r], sv);
                    l_run[s][r] = l_run[s][r] * __expf(m_run[s][r] - mn) + __expf(sv - mn);
                    m_run[s][r] = mn;
                }
            }
        }
    }

    // butterfly-merge across the 16 m-lanes (same n rows)
    #pragma unroll
    for (int s = 0; s < 2; ++s)
        #pragma unroll
        for (int r = 0; r < 4; ++r) {
            float m = m_run[s][r], l = l_run[s][r];
            #pragma unroll
            for (int off = 1; off < 16; off <<= 1) {
                float mo = __shfl_xor(m, off);
                float lo = __shfl_xor(l, off);
                float mn = fmaxf(m, mo);
                l = l * __expf(m - mn) + lo * __expf(mo - mn);
                m = mn;
            }
            if (mc == 0) { red_m[w][s * 16 + q * 4 + r] = m; red_l[w][s * 16 + q * 4 + r] = l; }
        }
    __syncthreads();
    if (t < 32) {
        float M = -1e30f;
        #pragma unroll
        for (int ww = 0; ww < 4; ++ww) M = fmaxf(M, red_m[ww][t]);
        float L = 0.0f;
        #pragma unroll
        for (int ww = 0; ww < 4; ++ww) L += red_l[ww][t] * __expf(red_m[ww][t] - M);
        Mout[(size_t)b * NN + n0 + t] = M;
        Linv[(size_t)b * NN + n0 + t] = 1.0f / L;
    }
}

// ---------------------------------------------------------------------------
// pv: out[c,m] = src[c,m] + gamma * sum_n h[c,n] * exp(S[n,m]-M[n]) * Linv[n]
// grid (64 m-tiles, 2 c-halves, 4 b), block 256. Per 64-n tile: MFMA S ->
// exp/pack -> PT LDS (per-wave rows: no cross-wave dep) -> MFMA PV.
// ---------------------------------------------------------------------------
__global__ __launch_bounds__(256)
void pv_kernel(const half_t* __restrict__ fT, const half_t* __restrict__ gT,
               const half_t* __restrict__ h,
               const float* __restrict__ Mbuf, const float* __restrict__ Lbuf,
               const float* __restrict__ src, const float* __restrict__ gamma,
               float* __restrict__ out)
{
    __shared__ half_t f_lds[64][40];     // 5 KB
    __shared__ half_t g_lds[64][40];     // 5 KB
    __shared__ half_t h_lds[128][72];    // 18 KB, pitch 72: conflict-free b128
    __shared__ half_t PT[64][72];        // 9 KB, P^T[m][n]
    __shared__ float M_s[64], Li_s[64];

    const int m0 = blockIdx.x * 64;
    const int c0 = blockIdx.y * 128;
    const int b  = blockIdx.z;
    const int t  = threadIdx.x;
    const int w = t >> 6, lane = t & 63, q = lane >> 4, mc = lane & 15;

    const half_t* fTb = fT + (size_t)b * NN * 32;
    const half_t* gTb = gT + (size_t)b * NN * 32;
    const half_t* hb  = h + (size_t)b * CC * NN;

    // stage gT once (64 rows x 4 chunks = 256)
    {
        int row = t >> 2, ch = t & 3;
        *(half8*)&g_lds[row][ch * 8] = *(const half8*)&gTb[(size_t)(m0 + row) * 32 + ch * 8];
    }

    floatx4 acc[8];
    #pragma unroll
    for (int j = 0; j < 8; ++j) acc[j] = (floatx4){0.f, 0.f, 0.f, 0.f};

    for (int nt = 0; nt < NN; nt += 64) {
        __syncthreads();                       // prior reads done before restage
        {   // fT tile: 64 rows x 4 chunks = 256
            int row = t >> 2, ch = t & 3;
            *(half8*)&f_lds[row][ch * 8] = *(const half8*)&fTb[(size_t)(nt + row) * 32 + ch * 8];
        }
        #pragma unroll
        for (int i = 0; i < 4; ++i) {          // h tile: 128 rows x 8 chunks
            int idx = t + 256 * i, row = idx >> 3, ch = idx & 7;
            *(half8*)&h_lds[row][ch * 8] =
                *(const half8*)&hb[(size_t)(c0 + row) * NN + nt + ch * 8];
        }
        if (t < 64) {
            M_s[t]  = Mbuf[(size_t)b * NN + nt + t];
            Li_s[t] = Lbuf[(size_t)b * NN + nt + t];
        }
        __syncthreads();

        // ---- S + P for this wave's m-strip (w), all 4 n-strips
        half8 bS = *(const half8*)&g_lds[w * 16 + mc][q * 8];
        #pragma unroll
        for (int s = 0; s < 4; ++s) {
            half8 af = *(const half8*)&f_lds[s * 16 + mc][q * 8];
            floatx4 S = __builtin_amdgcn_mfma_f32_16x16x32_f16(
                af, bS, (floatx4){0.f, 0.f, 0.f, 0.f}, 0, 0, 0);
            half4 p;
            #pragma unroll
            for (int r = 0; r < 4; ++r) {
                int n = s * 16 + q * 4 + r;
                p[r] = (half_t)(__expf(S[r] - M_s[n]) * Li_s[n]);
            }
            *(half4*)&PT[w * 16 + mc][s * 16 + q * 4] = p;   // b64, same-wave only
        }

        // ---- PV: acc[c-strip] += h . P   (B-frags from our own PT rows)
        #pragma unroll
        for (int kb = 0; kb < 2; ++kb) {
            half8 bP = *(const half8*)&PT[w * 16 + mc][kb * 32 + q * 8];
            #pragma unroll
            for (int j = 0; j < 8; ++j) {
                half8 ah = *(const half8*)&h_lds[j * 16 + mc][kb * 32 + q * 8];
                acc[j] = __builtin_amdgcn_mfma_f32_16x16x32_f16(ah, bP, acc[j], 0, 0, 0);
            }
        }
    }

    // ---- epilogue: out = src + gamma * acc
    const float gm = gamma[0];
    const float* srcb = src + (size_t)b * CC * NN;
    float* outb = out + (size_t)b * CC * NN;
    #pragma unroll
    for (int j = 0; j < 8; ++j)
        #pragma unroll
        for (int r = 0; r < 4; ++r) {
            size_t idx = (size_t)(c0 + j * 16 + q * 4 + r) * NN + m0 + w * 16 + mc;
            outb[idx] = fmaf(gm, acc[j][r], srcb[idx]);
        }
}

// ---------------------------------------------------------------------------
extern "C" void kernel_launch(void* const* d_in, const int* in_sizes, int n_in,
                              void* d_out, int out_size, void* d_ws, size_t ws_size,
                              hipStream_t stream)
{
    const float* x   = (const float*)d_in[0];
    const float* y   = (const float*)d_in[1];
    const float* Wfx = (const float*)d_in[2];
    const float* bfx = (const float*)d_in[3];
    const float* Wgx = (const float*)d_in[4];
    const float* bgx = (const float*)d_in[5];
    const float* Whx = (const float*)d_in[6];
    const float* bhx = (const float*)d_in[7];
    const float* Wfy = (const float*)d_in[8];
    const float* bfy = (const float*)d_in[9];
    const float* Wgy = (const float*)d_in[10];
    const float* bgy = (const float*)d_in[11];
    const float* Why = (const float*)d_in[12];
    const float* bhy = (const float*)d_in[13];
    const float* gam = (const float*)d_in[14];

    // workspace: fp16 region then fp32 stats
    const size_t SZ_FG = (size_t)BB * NN * 32;   // 524288 halves (1 MB)
    const size_t SZ_H  = (size_t)BB * CC * NN;   // 4194304 halves (8 MB)
    const size_t SZ_ML = (size_t)BB * NN;        // 16384 floats
    half_t* fxT = (half_t*)d_ws;
    half_t* gxT = fxT + SZ_FG;
    half_t* fyT = gxT + SZ_FG;
    half_t* gyT = fyT + SZ_FG;
    half_t* hx  = gyT + SZ_FG;
    half_t* hy  = hx + SZ_H;
    float*  Mx  = (float*)(hy + SZ_H);
    float*  Lx  = Mx + SZ_ML;
    float*  My  = Lx + SZ_ML;
    float*  Ly  = My + SZ_ML;

    float* outx = (float*)d_out;
    float* outy = outx + (size_t)BB * CC * NN;

    dim3 gproj(NN / 64, BB);
    proj_fg_kernel<<<gproj, 256, 0, stream>>>(x, Wfx, bfx, fxT);
    proj_fg_kernel<<<gproj, 256, 0, stream>>>(x, Wgx, bgx, gxT);
    proj_fg_kernel<<<gproj, 256, 0, stream>>>(y, Wfy, bfy, fyT);
    proj_fg_kernel<<<gproj, 256, 0, stream>>>(y, Wgy, bgy, gyT);
    proj_h_kernel <<<gproj, 256, 0, stream>>>(x, Whx, bhx, hx);
    proj_h_kernel <<<gproj, 256, 0, stream>>>(y, Why, bhy, hy);

    dim3 gstat(NN / 32, BB);
    stats_kernel<<<gstat, 256, 0, stream>>>(fyT, gxT, Mx, Lx);  // att_x rows: fy
    stats_kernel<<<gstat, 256, 0, stream>>>(fxT, gyT, My, Ly);  // att_y rows: fx

    dim3 gpv(NN / 64, 2, BB);
    pv_kernel<<<gpv, 256, 0, stream>>>(fyT, gxT, hx, Mx, Lx, x, gam, outx);
    pv_kernel<<<gpv, 256, 0, stream>>>(fxT, gyT, hy, My, Ly, y, gam, outy);
}

// Round 3
// 537.210 us; speedup vs baseline: 5.3070x; 1.3431x over previous
//
#include <hip/hip_runtime.h>

// B=4, C=256, C8=32, N=4096. fp16 MFMA (16x16x32) for all GEMMs.
#define BB 4
#define CC 256
#define NN 4096

typedef _Float16 half_t;
typedef __attribute__((ext_vector_type(8))) _Float16 half8;
typedef __attribute__((ext_vector_type(4))) _Float16 half4;
typedef __attribute__((ext_vector_type(4))) float floatx4;

// ---------------------------------------------------------------------------
// cvt_w: cast the six weight matrices to fp16 (flat copy). grid (64, 6).
// ---------------------------------------------------------------------------
__global__ __launch_bounds__(256)
void cvt_w_kernel(const float* __restrict__ Wfx, const float* __restrict__ Wgx,
                  const float* __restrict__ Whx, const float* __restrict__ Wfy,
                  const float* __restrict__ Wgy, const float* __restrict__ Why,
                  half_t* __restrict__ oWfx, half_t* __restrict__ oWgx,
                  half_t* __restrict__ oWhx, half_t* __restrict__ oWfy,
                  half_t* __restrict__ oWgy, half_t* __restrict__ oWhy)
{
    const float* src; half_t* dst; int n;
    switch (blockIdx.y) {
        case 0: src = Wfx; dst = oWfx; n = 32 * CC; break;
        case 1: src = Wgx; dst = oWgx; n = 32 * CC; break;
        case 2: src = Whx; dst = oWhx; n = CC * CC; break;
        case 3: src = Wfy; dst = oWfy; n = 32 * CC; break;
        case 4: src = Wgy; dst = oWgy; n = 32 * CC; break;
        default: src = Why; dst = oWhy; n = CC * CC; break;
    }
    int idx = (blockIdx.x * 256 + threadIdx.x) * 4;
    if (idx >= n) return;
    float4 v = *(const float4*)&src[idx];
    half4 h; h[0] = (half_t)v.x; h[1] = (half_t)v.y; h[2] = (half_t)v.z; h[3] = (half_t)v.w;
    *(half4*)&dst[idx] = h;
}

// ---------------------------------------------------------------------------
// transpose_cvt: xT[b][n][c] fp16 from x[b][c][n] fp32.  grid (64, 4, 4).
// Reads stream through L1 (64x64 f32 tile = 16 KB); writes coalesced half8.
// ---------------------------------------------------------------------------
__global__ __launch_bounds__(256)
void transpose_cvt_kernel(const float* __restrict__ in, half_t* __restrict__ outT)
{
    const int n0 = blockIdx.x * 64;
    const int c0 = blockIdx.y * 64;
    const int b  = blockIdx.z;
    const int t  = threadIdx.x;
    const int ch = t & 7, nl = t >> 3;            // 8 c-chunks x 32 n
    const float* inb = in + (size_t)b * CC * NN;
    half_t* outb = outT + (size_t)b * NN * CC;

    #pragma unroll
    for (int p = 0; p < 2; ++p) {
        int n = n0 + nl + 32 * p;
        half8 hv;
        #pragma unroll
        for (int j = 0; j < 8; ++j)
            hv[j] = (half_t)inb[(size_t)(c0 + 8 * ch + j) * NN + n];
        *(half8*)&outb[(size_t)n * CC + c0 + 8 * ch] = hv;   // 128B runs per 8 lanes
    }
}

// ---------------------------------------------------------------------------
// proj_fg (MFMA): fT[n][32], gT[n][32] = xT @ {Wf,Wg}^T + bias.
// grid (64, 4), block 256. Wave w: n-strip w*16; 4 o-tiles (f0,f1,g0,g1).
// All fragments loaded straight from global (L2/L1-resident). No LDS.
// ---------------------------------------------------------------------------
__global__ __launch_bounds__(256)
void proj_fg_kernel(const half_t* __restrict__ xT,
                    const half_t* __restrict__ Wf, const half_t* __restrict__ Wg,
                    const float* __restrict__ bf, const float* __restrict__ bg,
                    half_t* __restrict__ fT, half_t* __restrict__ gT)
{
    const int n0 = blockIdx.x * 64;
    const int b  = blockIdx.y;
    const int t  = threadIdx.x;
    const int w = t >> 6, lane = t & 63, q = lane >> 4, mc = lane & 15;
    const half_t* xTb = xT + (size_t)b * NN * CC;

    floatx4 acc[4];
    #pragma unroll
    for (int i = 0; i < 4; ++i) {
        float bv = (i < 2 ? bf : bg)[(i & 1) * 16 + mc];
        acc[i] = (floatx4){bv, bv, bv, bv};
    }

    #pragma unroll
    for (int ks = 0; ks < 8; ++ks) {
        int k0 = ks * 32 + q * 8;
        half8 af = *(const half8*)&xTb[(size_t)(n0 + w * 16 + mc) * CC + k0];
        #pragma unroll
        for (int i = 0; i < 4; ++i) {
            const half_t* Ws = (i < 2) ? Wf : Wg;
            half8 bfr = *(const half8*)&Ws[(size_t)((i & 1) * 16 + mc) * CC + k0];
            acc[i] = __builtin_amdgcn_mfma_f32_16x16x32_f16(af, bfr, acc[i], 0, 0, 0);
        }
    }

    // C-layout: col(o) = mc, row(n) = q*4+r
    #pragma unroll
    for (int i = 0; i < 4; ++i) {
        half_t* dst = (i < 2) ? fT : gT;
        #pragma unroll
        for (int r = 0; r < 4; ++r) {
            int n = n0 + w * 16 + q * 4 + r;
            dst[((size_t)b * NN + n) * 32 + (i & 1) * 16 + mc] = (half_t)acc[i][r];
        }
    }
}

// ---------------------------------------------------------------------------
// proj_h (MFMA): h[o][n] = Wh @ x + bias.  grid (64 n-tiles, 2 o-half, 4 b).
// Wave w: o-strip o0+w*32 (2 tiles) x 64 n (4 tiles). Direct global frags.
// ---------------------------------------------------------------------------
__global__ __launch_bounds__(256)
void proj_h_kernel(const half_t* __restrict__ xT, const half_t* __restrict__ Wh,
                   const float* __restrict__ bh, half_t* __restrict__ h)
{
    const int n0 = blockIdx.x * 64;
    const int o0 = blockIdx.y * 128;
    const int b  = blockIdx.z;
    const int t  = threadIdx.x;
    const int w = t >> 6, lane = t & 63, q = lane >> 4, mc = lane & 15;
    const half_t* xTb = xT + (size_t)b * NN * CC;
    half_t* hb = h + (size_t)b * CC * NN;

    floatx4 acc[2][4];
    #pragma unroll
    for (int j = 0; j < 2; ++j) {
        floatx4 bv;
        #pragma unroll
        for (int r = 0; r < 4; ++r) bv[r] = bh[o0 + w * 32 + j * 16 + q * 4 + r];
        #pragma unroll
        for (int i = 0; i < 4; ++i) acc[j][i] = bv;
    }

    #pragma unroll
    for (int ks = 0; ks < 8; ++ks) {
        int k0 = ks * 32 + q * 8;
        half8 a0 = *(const half8*)&Wh[(size_t)(o0 + w * 32 + mc) * CC + k0];
        half8 a1 = *(const half8*)&Wh[(size_t)(o0 + w * 32 + 16 + mc) * CC + k0];
        #pragma unroll
        for (int i = 0; i < 4; ++i) {
            half8 bfr = *(const half8*)&xTb[(size_t)(n0 + i * 16 + mc) * CC + k0];
            acc[0][i] = __builtin_amdgcn_mfma_f32_16x16x32_f16(a0, bfr, acc[0][i], 0, 0, 0);
            acc[1][i] = __builtin_amdgcn_mfma_f32_16x16x32_f16(a1, bfr, acc[1][i], 0, 0, 0);
        }
    }

    // C-layout: col(n) = mc, row(o) = q*4+r
    #pragma unroll
    for (int j = 0; j < 2; ++j)
        #pragma unroll
        for (int i = 0; i < 4; ++i)
            #pragma unroll
            for (int r = 0; r < 4; ++r) {
                int o = o0 + w * 32 + j * 16 + q * 4 + r;
                hb[(size_t)o * NN + n0 + i * 16 + mc] = (half_t)acc[j][i][r];
            }
}

// ---------------------------------------------------------------------------
// stats: Linv[n] = 1 / sum_m exp(S[n,m]), no max shift (|S| << 88).
// grid (128, 4), block 256. Pure global-frag MFMA + exp; LDS only for reduce.
// ---------------------------------------------------------------------------
__global__ __launch_bounds__(256)
void stats_kernel(const half_t* __restrict__ fT, const half_t* __restrict__ gT,
                  float* __restrict__ Linv)
{
    __shared__ float red_l[4][32];
    const int b  = blockIdx.y;
    const int n0 = blockIdx.x * 32;
    const int t  = threadIdx.x;
    const int w = t >> 6, lane = t & 63, q = lane >> 4, mc = lane & 15;
    const half_t* fTb = fT + (size_t)b * NN * 32;
    const half_t* gTb = gT + (size_t)b * NN * 32;

    half8 a0 = *(const half8*)&fTb[(size_t)(n0 + mc) * 32 + q * 8];
    half8 a1 = *(const half8*)&fTb[(size_t)(n0 + 16 + mc) * 32 + q * 8];

    float l0[4] = {0.f, 0.f, 0.f, 0.f}, l1[4] = {0.f, 0.f, 0.f, 0.f};
    for (int it = 0; it < NN / 64; ++it) {
        int m = (it * 4 + w) * 16 + mc;
        half8 bfr = *(const half8*)&gTb[(size_t)m * 32 + q * 8];
        floatx4 S0 = __builtin_amdgcn_mfma_f32_16x16x32_f16(a0, bfr, (floatx4){0.f,0.f,0.f,0.f}, 0, 0, 0);
        floatx4 S1 = __builtin_amdgcn_mfma_f32_16x16x32_f16(a1, bfr, (floatx4){0.f,0.f,0.f,0.f}, 0, 0, 0);
        #pragma unroll
        for (int r = 0; r < 4; ++r) { l0[r] += __expf(S0[r]); l1[r] += __expf(S1[r]); }
    }
    // sum over the 16 m-lanes (lane bits 0..3)
    #pragma unroll
    for (int r = 0; r < 4; ++r) {
        #pragma unroll
        for (int off = 1; off < 16; off <<= 1) {
            l0[r] += __shfl_xor(l0[r], off);
            l1[r] += __shfl_xor(l1[r], off);
        }
    }
    if (mc == 0)
        #pragma unroll
        for (int r = 0; r < 4; ++r) {
            red_l[w][q * 4 + r]      = l0[r];
            red_l[w][16 + q * 4 + r] = l1[r];
        }
    __syncthreads();
    if (t < 32) {
        float L = red_l[0][t] + red_l[1][t] + red_l[2][t] + red_l[3][t];
        Linv[(size_t)b * NN + n0 + t] = 1.0f / L;
    }
}

// ---------------------------------------------------------------------------
// pv: out[c,m] = src[c,m] + gamma * sum_n h[c,n] * exp(S[n,m]) * Linv[n]
// grid (64, 2, 4), block 256. f/g frags from global; h staged in LDS; P
// transposed through per-wave LDS rows (no cross-wave dependency).
// ---------------------------------------------------------------------------
__global__ __launch_bounds__(256)
void pv_kernel(const half_t* __restrict__ fT, const half_t* __restrict__ gT,
               const half_t* __restrict__ h, const float* __restrict__ Lbuf,
               const float* __restrict__ src, const float* __restrict__ gamma,
               float* __restrict__ out)
{
    __shared__ half_t h_lds[128][72];    // 18 KB, pitch 72: conflict-free b128
    __shared__ half_t PT[64][72];        // 9 KB, P^T[m][n]
    __shared__ float Li_s[64];

    const int m0 = blockIdx.x * 64;
    const int c0 = blockIdx.y * 128;
    const int b  = blockIdx.z;
    const int t  = threadIdx.x;
    const int w = t >> 6, lane = t & 63, q = lane >> 4, mc = lane & 15;

    const half_t* fTb = fT + (size_t)b * NN * 32;
    const half_t* gTb = gT + (size_t)b * NN * 32;
    const half_t* hb  = h + (size_t)b * CC * NN;

    half8 bS = *(const half8*)&gTb[(size_t)(m0 + w * 16 + mc) * 32 + q * 8];

    floatx4 acc[8];
    #pragma unroll
    for (int j = 0; j < 8; ++j) acc[j] = (floatx4){0.f, 0.f, 0.f, 0.f};

    for (int nt = 0; nt < NN; nt += 64) {
        __syncthreads();                       // prior reads done before restage
        #pragma unroll
        for (int i = 0; i < 4; ++i) {          // h tile: 128 rows x 8 chunks
            int idx = t + 256 * i, row = idx >> 3, ch = idx & 7;
            *(half8*)&h_lds[row][ch * 8] =
                *(const half8*)&hb[(size_t)(c0 + row) * NN + nt + ch * 8];
        }
        if (t < 64) Li_s[t] = Lbuf[(size_t)b * NN + nt + t];
        __syncthreads();

        // ---- S + P for this wave's m-strip, all 4 n-strips
        #pragma unroll
        for (int s = 0; s < 4; ++s) {
            half8 af = *(const half8*)&fTb[(size_t)(nt + s * 16 + mc) * 32 + q * 8];
            floatx4 S = __builtin_amdgcn_mfma_f32_16x16x32_f16(
                af, bS, (floatx4){0.f, 0.f, 0.f, 0.f}, 0, 0, 0);
            half4 p;
            #pragma unroll
            for (int r = 0; r < 4; ++r) {
                int n = s * 16 + q * 4 + r;
                p[r] = (half_t)(__expf(S[r]) * Li_s[n]);
            }
            *(half4*)&PT[w * 16 + mc][s * 16 + q * 4] = p;   // same-wave rows only
        }

        // ---- PV: acc[c-strip] += h . P
        #pragma unroll
        for (int kb = 0; kb < 2; ++kb) {
            half8 bP = *(const half8*)&PT[w * 16 + mc][kb * 32 + q * 8];
            #pragma unroll
            for (int j = 0; j < 8; ++j) {
                half8 ah = *(const half8*)&h_lds[j * 16 + mc][kb * 32 + q * 8];
                acc[j] = __builtin_amdgcn_mfma_f32_16x16x32_f16(ah, bP, acc[j], 0, 0, 0);
            }
        }
    }

    const float gm = gamma[0];
    const float* srcb = src + (size_t)b * CC * NN;
    float* outb = out + (size_t)b * CC * NN;
    #pragma unroll
    for (int j = 0; j < 8; ++j)
        #pragma unroll
        for (int r = 0; r < 4; ++r) {
            size_t idx = (size_t)(c0 + j * 16 + q * 4 + r) * NN + m0 + w * 16 + mc;
            outb[idx] = fmaf(gm, acc[j][r], srcb[idx]);
        }
}

// ---------------------------------------------------------------------------
extern "C" void kernel_launch(void* const* d_in, const int* in_sizes, int n_in,
                              void* d_out, int out_size, void* d_ws, size_t ws_size,
                              hipStream_t stream)
{
    const float* x   = (const float*)d_in[0];
    const float* y   = (const float*)d_in[1];
    const float* Wfx = (const float*)d_in[2];
    const float* bfx = (const float*)d_in[3];
    const float* Wgx = (const float*)d_in[4];
    const float* bgx = (const float*)d_in[5];
    const float* Whx = (const float*)d_in[6];
    const float* bhx = (const float*)d_in[7];
    const float* Wfy = (const float*)d_in[8];
    const float* bfy = (const float*)d_in[9];
    const float* Wgy = (const float*)d_in[10];
    const float* bgy = (const float*)d_in[11];
    const float* Why = (const float*)d_in[12];
    const float* bhy = (const float*)d_in[13];
    const float* gam = (const float*)d_in[14];

    // workspace (halves): xT (reused for x then y), hx, hy, f/g, W fp16, L f32
    const size_t SZ_XT = (size_t)BB * NN * CC;   // 4,194,304
    const size_t SZ_FG = (size_t)BB * NN * 32;   // 524,288
    half_t* xT    = (half_t*)d_ws;
    half_t* hx    = xT + SZ_XT;
    half_t* hy    = hx + SZ_XT;
    half_t* fxT   = hy + SZ_XT;
    half_t* gxT   = fxT + SZ_FG;
    half_t* fyT   = gxT + SZ_FG;
    half_t* gyT   = fyT + SZ_FG;
    half_t* Wfx_h = gyT + SZ_FG;
    half_t* Wgx_h = Wfx_h + 32 * CC;
    half_t* Wfy_h = Wgx_h + 32 * CC;
    half_t* Wgy_h = Wfy_h + 32 * CC;
    half_t* Whx_h = Wgy_h + 32 * CC;
    half_t* Why_h = Whx_h + CC * CC;
    float*  Lx    = (float*)(Why_h + CC * CC);
    float*  Ly    = Lx + (size_t)BB * NN;

    float* outx = (float*)d_out;
    float* outy = outx + (size_t)BB * CC * NN;

    cvt_w_kernel<<<dim3(64, 6), 256, 0, stream>>>(Wfx, Wgx, Whx, Wfy, Wgy, Why,
                                                  Wfx_h, Wgx_h, Whx_h, Wfy_h, Wgy_h, Why_h);

    // x pipeline
    transpose_cvt_kernel<<<dim3(64, 4, 4), 256, 0, stream>>>(x, xT);
    proj_fg_kernel<<<dim3(64, 4), 256, 0, stream>>>(xT, Wfx_h, Wgx_h, bfx, bgx, fxT, gxT);
    proj_h_kernel<<<dim3(64, 2, 4), 256, 0, stream>>>(xT, Whx_h, bhx, hx);
    // y pipeline (reuses xT buffer)
    transpose_cvt_kernel<<<dim3(64, 4, 4), 256, 0, stream>>>(y, xT);
    proj_fg_kernel<<<dim3(64, 4), 256, 0, stream>>>(xT, Wfy_h, Wgy_h, bfy, bgy, fyT, gyT);
    proj_h_kernel<<<dim3(64, 2, 4), 256, 0, stream>>>(xT, Why_h, bhy, hy);

    stats_kernel<<<dim3(128, 4), 256, 0, stream>>>(fyT, gxT, Lx);  // att_x rows: fy
    stats_kernel<<<dim3(128, 4), 256, 0, stream>>>(fxT, gyT, Ly);  // att_y rows: fx

    pv_kernel<<<dim3(64, 2, 4), 256, 0, stream>>>(fyT, gxT, hx, Lx, x, gam, outx);
    pv_kernel<<<dim3(64, 2, 4), 256, 0, stream>>>(fxT, gyT, hy, Ly, y, gam, outy);
}

// Round 4
// 341.215 us; speedup vs baseline: 8.3554x; 1.5744x over previous
//
#include <hip/hip_runtime.h>

// B=4, C=256, C8=32, N=4096. fp16 MFMA: 16x16x32 (S, proj), 32x32x16 (PV).
#define BB 4
#define CC 256
#define NN 4096

typedef _Float16 half_t;
typedef __attribute__((ext_vector_type(8))) _Float16 half8;
typedef __attribute__((ext_vector_type(4))) _Float16 half4;
typedef __attribute__((ext_vector_type(4))) float floatx4;
typedef __attribute__((ext_vector_type(16))) float floatx16;

// ---------------------------------------------------------------------------
// cvt_w: cast the six weight matrices to fp16. grid (64, 6).
// ---------------------------------------------------------------------------
__global__ __launch_bounds__(256)
void cvt_w_kernel(const float* __restrict__ Wfx, const float* __restrict__ Wgx,
                  const float* __restrict__ Whx, const float* __restrict__ Wfy,
                  const float* __restrict__ Wgy, const float* __restrict__ Why,
                  half_t* __restrict__ oWfx, half_t* __restrict__ oWgx,
                  half_t* __restrict__ oWhx, half_t* __restrict__ oWfy,
                  half_t* __restrict__ oWgy, half_t* __restrict__ oWhy)
{
    const float* src; half_t* dst; int n;
    switch (blockIdx.y) {
        case 0: src = Wfx; dst = oWfx; n = 32 * CC; break;
        case 1: src = Wgx; dst = oWgx; n = 32 * CC; break;
        case 2: src = Whx; dst = oWhx; n = CC * CC; break;
        case 3: src = Wfy; dst = oWfy; n = 32 * CC; break;
        case 4: src = Wgy; dst = oWgy; n = 32 * CC; break;
        default: src = Why; dst = oWhy; n = CC * CC; break;
    }
    int idx = (blockIdx.x * 256 + threadIdx.x) * 4;
    if (idx >= n) return;
    float4 v = *(const float4*)&src[idx];
    half4 h; h[0] = (half_t)v.x; h[1] = (half_t)v.y; h[2] = (half_t)v.z; h[3] = (half_t)v.w;
    *(half4*)&dst[idx] = h;
}

// ---------------------------------------------------------------------------
// transpose_cvt: xT[b][n][c] fp16 from in[b][c][n] fp32. grid (64, 4, 8).
// z = b + 4*sel (sel 0: x->xTx, 1: y->xTy).
// ---------------------------------------------------------------------------
__global__ __launch_bounds__(256)
void transpose_cvt_kernel(const float* __restrict__ x, const float* __restrict__ y,
                          half_t* __restrict__ xTx, half_t* __restrict__ xTy)
{
    const int n0 = blockIdx.x * 64;
    const int c0 = blockIdx.y * 64;
    const int b  = blockIdx.z & 3;
    const int sel = blockIdx.z >> 2;
    const float* in = sel ? y : x;
    half_t* outT = sel ? xTy : xTx;
    const int t  = threadIdx.x;
    const int ch = t & 7, nl = t >> 3;            // 8 c-chunks x 32 n
    const float* inb = in + (size_t)b * CC * NN;
    half_t* outb = outT + (size_t)b * NN * CC;

    #pragma unroll
    for (int p = 0; p < 2; ++p) {
        int n = n0 + nl + 32 * p;
        half8 hv;
        #pragma unroll
        for (int j = 0; j < 8; ++j)
            hv[j] = (half_t)inb[(size_t)(c0 + 8 * ch + j) * NN + n];
        *(half8*)&outb[(size_t)n * CC + c0 + 8 * ch] = hv;
    }
}

// ---------------------------------------------------------------------------
// proj_fg (MFMA): fT[n][32], gT[n][32]. grid (64, 4, 2): z = sel.
// ---------------------------------------------------------------------------
__global__ __launch_bounds__(256)
void proj_fg_kernel(const half_t* __restrict__ xTx, const half_t* __restrict__ xTy,
                    const half_t* __restrict__ Wfx, const half_t* __restrict__ Wgx,
                    const half_t* __restrict__ Wfy, const half_t* __restrict__ Wgy,
                    const float* __restrict__ bfx, const float* __restrict__ bgx,
                    const float* __restrict__ bfy, const float* __restrict__ bgy,
                    half_t* __restrict__ fxT, half_t* __restrict__ gxT,
                    half_t* __restrict__ fyT, half_t* __restrict__ gyT)
{
    const int n0 = blockIdx.x * 64;
    const int b  = blockIdx.y;
    const int sel = blockIdx.z;
    const half_t* xT = sel ? xTy : xTx;
    const half_t* Wf = sel ? Wfy : Wfx;
    const half_t* Wg = sel ? Wgy : Wgx;
    const float*  bf = sel ? bfy : bfx;
    const float*  bg = sel ? bgy : bgx;
    half_t* fT = sel ? fyT : fxT;
    half_t* gT = sel ? gyT : gxT;

    const int t  = threadIdx.x;
    const int w = t >> 6, lane = t & 63, q = lane >> 4, mc = lane & 15;
    const half_t* xTb = xT + (size_t)b * NN * CC;

    floatx4 acc[4];
    #pragma unroll
    for (int i = 0; i < 4; ++i) {
        float bv = (i < 2 ? bf : bg)[(i & 1) * 16 + mc];
        acc[i] = (floatx4){bv, bv, bv, bv};
    }

    #pragma unroll
    for (int ks = 0; ks < 8; ++ks) {
        int k0 = ks * 32 + q * 8;
        half8 af = *(const half8*)&xTb[(size_t)(n0 + w * 16 + mc) * CC + k0];
        #pragma unroll
        for (int i = 0; i < 4; ++i) {
            const half_t* Ws = (i < 2) ? Wf : Wg;
            half8 bfr = *(const half8*)&Ws[(size_t)((i & 1) * 16 + mc) * CC + k0];
            acc[i] = __builtin_amdgcn_mfma_f32_16x16x32_f16(af, bfr, acc[i], 0, 0, 0);
        }
    }

    #pragma unroll
    for (int i = 0; i < 4; ++i) {
        half_t* dst = (i < 2) ? fT : gT;
        #pragma unroll
        for (int r = 0; r < 4; ++r) {
            int n = n0 + w * 16 + q * 4 + r;
            dst[((size_t)b * NN + n) * 32 + (i & 1) * 16 + mc] = (half_t)acc[i][r];
        }
    }
}

// ---------------------------------------------------------------------------
// proj_h (MFMA): h[o][n]. grid (64, 2, 8): z = b + 4*sel.
// ---------------------------------------------------------------------------
__global__ __launch_bounds__(256)
void proj_h_kernel(const half_t* __restrict__ xTx, const half_t* __restrict__ xTy,
                   const half_t* __restrict__ Whx, const half_t* __restrict__ Why,
                   const float* __restrict__ bhx, const float* __restrict__ bhy,
                   half_t* __restrict__ hx, half_t* __restrict__ hy)
{
    const int n0 = blockIdx.x * 64;
    const int o0 = blockIdx.y * 128;
    const int b  = blockIdx.z & 3;
    const int sel = blockIdx.z >> 2;
    const half_t* xT = sel ? xTy : xTx;
    const half_t* Wh = sel ? Why : Whx;
    const float*  bh = sel ? bhy : bhx;
    half_t* h = sel ? hy : hx;

    const int t  = threadIdx.x;
    const int w = t >> 6, lane = t & 63, q = lane >> 4, mc = lane & 15;
    const half_t* xTb = xT + (size_t)b * NN * CC;
    half_t* hb = h + (size_t)b * CC * NN;

    floatx4 acc[2][4];
    #pragma unroll
    for (int j = 0; j < 2; ++j) {
        floatx4 bv;
        #pragma unroll
        for (int r = 0; r < 4; ++r) bv[r] = bh[o0 + w * 32 + j * 16 + q * 4 + r];
        #pragma unroll
        for (int i = 0; i < 4; ++i) acc[j][i] = bv;
    }

    #pragma unroll
    for (int ks = 0; ks < 8; ++ks) {
        int k0 = ks * 32 + q * 8;
        half8 a0 = *(const half8*)&Wh[(size_t)(o0 + w * 32 + mc) * CC + k0];
        half8 a1 = *(const half8*)&Wh[(size_t)(o0 + w * 32 + 16 + mc) * CC + k0];
        #pragma unroll
        for (int i = 0; i < 4; ++i) {
            half8 bfr = *(const half8*)&xTb[(size_t)(n0 + i * 16 + mc) * CC + k0];
            acc[0][i] = __builtin_amdgcn_mfma_f32_16x16x32_f16(a0, bfr, acc[0][i], 0, 0, 0);
            acc[1][i] = __builtin_amdgcn_mfma_f32_16x16x32_f16(a1, bfr, acc[1][i], 0, 0, 0);
        }
    }

    #pragma unroll
    for (int j = 0; j < 2; ++j)
        #pragma unroll
        for (int i = 0; i < 4; ++i)
            #pragma unroll
            for (int r = 0; r < 4; ++r) {
                int o = o0 + w * 32 + j * 16 + q * 4 + r;
                hb[(size_t)o * NN + n0 + i * 16 + mc] = (half_t)acc[j][i][r];
            }
}

// ---------------------------------------------------------------------------
// stats: Llog2[n] = -log2( sum_m exp(S[n,m]) ). grid (128, 4, 2).
// ---------------------------------------------------------------------------
__global__ __launch_bounds__(256)
void stats_kernel(const half_t* __restrict__ fT0, const half_t* __restrict__ gT0,
                  const half_t* __restrict__ fT1, const half_t* __restrict__ gT1,
                  float* __restrict__ L0, float* __restrict__ L1)
{
    __shared__ float red_l[4][32];
    const int b  = blockIdx.y;
    const int sel = blockIdx.z;
    const half_t* fT = sel ? fT1 : fT0;
    const half_t* gT = sel ? gT1 : gT0;
    float* Lout = sel ? L1 : L0;

    const int n0 = blockIdx.x * 32;
    const int t  = threadIdx.x;
    const int w = t >> 6, lane = t & 63, q = lane >> 4, mc = lane & 15;
    const half_t* fTb = fT + (size_t)b * NN * 32;
    const half_t* gTb = gT + (size_t)b * NN * 32;

    half8 a0 = *(const half8*)&fTb[(size_t)(n0 + mc) * 32 + q * 8];
    half8 a1 = *(const half8*)&fTb[(size_t)(n0 + 16 + mc) * 32 + q * 8];

    float l0[4] = {0.f, 0.f, 0.f, 0.f}, l1[4] = {0.f, 0.f, 0.f, 0.f};
    for (int it = 0; it < NN / 64; ++it) {
        int m = (it * 4 + w) * 16 + mc;
        half8 bfr = *(const half8*)&gTb[(size_t)m * 32 + q * 8];
        floatx4 S0 = __builtin_amdgcn_mfma_f32_16x16x32_f16(a0, bfr, (floatx4){0.f,0.f,0.f,0.f}, 0, 0, 0);
        floatx4 S1 = __builtin_amdgcn_mfma_f32_16x16x32_f16(a1, bfr, (floatx4){0.f,0.f,0.f,0.f}, 0, 0, 0);
        #pragma unroll
        for (int r = 0; r < 4; ++r) { l0[r] += __expf(S0[r]); l1[r] += __expf(S1[r]); }
    }
    #pragma unroll
    for (int r = 0; r < 4; ++r) {
        #pragma unroll
        for (int off = 1; off < 16; off <<= 1) {
            l0[r] += __shfl_xor(l0[r], off);
            l1[r] += __shfl_xor(l1[r], off);
        }
    }
    if (mc == 0)
        #pragma unroll
        for (int r = 0; r < 4; ++r) {
            red_l[w][q * 4 + r]      = l0[r];
            red_l[w][16 + q * 4 + r] = l1[r];
        }
    __syncthreads();
    if (t < 32) {
        float L = red_l[0][t] + red_l[1][t] + red_l[2][t] + red_l[3][t];
        Lout[(size_t)b * NN + n0 + t] = -log2f(L);
    }
}

// ---------------------------------------------------------------------------
// pv: out[c,m] = src[c,m] + gamma * sum_n h[c,n] * exp2(S*log2e + Llog2[n]).
// grid (64, 2, 8): z = b + 4*sel. Block tile 128c x 64m; wave = 64c x 32m.
// S via 16x16x32 (per-wave 16m strip -> PT), PV via 32x32x16 (2 A + 1 B per
// 16-k chunk). 2 barriers/tile; next-tile f/h prefetched during PV phase.
// ---------------------------------------------------------------------------
__global__ __launch_bounds__(256)
void pv_kernel(const half_t* __restrict__ fT0, const half_t* __restrict__ gT0,
               const half_t* __restrict__ h0, const float* __restrict__ L0,
               const float* __restrict__ src0, float* __restrict__ out0,
               const half_t* __restrict__ fT1, const half_t* __restrict__ gT1,
               const half_t* __restrict__ h1, const float* __restrict__ L1,
               const float* __restrict__ src1, float* __restrict__ out1,
               const float* __restrict__ gamma)
{
    __shared__ half_t h_lds[128][72];    // 18 KB, pitch 72 -> uniform quads
    __shared__ half_t PT[64][72];        // 9 KB, P^T[m][n]

    const int m0 = blockIdx.x * 64;
    const int c0 = blockIdx.y * 128;
    const int b  = blockIdx.z & 3;
    const int sel = blockIdx.z >> 2;
    const half_t* fT = sel ? fT1 : fT0;
    const half_t* gT = sel ? gT1 : gT0;
    const half_t* h  = sel ? h1 : h0;
    const float*  Lg = sel ? L1 : L0;
    const float*  src = sel ? src1 : src0;
    float* out = sel ? out1 : out0;

    const int t = threadIdx.x;
    const int w = t >> 6, lane = t & 63;
    const int q = lane >> 4, mc = lane & 15;
    const int l5 = lane >> 5, l31 = lane & 31;

    const half_t* fTb = fT + (size_t)b * NN * 32;
    const half_t* gTb = gT + (size_t)b * NN * 32;
    const half_t* hb  = h + (size_t)b * CC * NN;
    const float*  Lb  = Lg + (size_t)b * NN;

    // persistent S B-frag: m = m0 + w*16 + mc, k = q*8..
    half8 gS = *(const half8*)&gTb[(size_t)(m0 + w * 16 + mc) * 32 + q * 8];

    // h stage addressing: thread covers rows srow+32i, chunk sch
    const int srow = t >> 3;    // 0..31
    const int sch  = t & 7;     // 0..7

    // prefetch tile 0
    half8 hpre[4], fpre[4];
    #pragma unroll
    for (int i = 0; i < 4; ++i)
        hpre[i] = *(const half8*)&hb[(size_t)(c0 + srow + 32 * i) * NN + sch * 8];
    #pragma unroll
    for (int s = 0; s < 4; ++s)
        fpre[s] = *(const half8*)&fTb[(size_t)(s * 16 + mc) * 32 + q * 8];

    floatx16 acc0, acc1;
    #pragma unroll
    for (int r = 0; r < 16; ++r) { acc0[r] = 0.f; acc1[r] = 0.f; }

    const int ca = (w >> 1) * 64;     // PV c-base for this wave
    const int mb = (w & 1) * 32;      // PV m-base (local)

    for (int nt = 0; nt < NN; nt += 64) {
        __syncthreads();              // A: previous PV reads done
        #pragma unroll
        for (int i = 0; i < 4; ++i)
            *(half8*)&h_lds[srow + 32 * i][sch * 8] = hpre[i];

        // ---- S phase: this wave's 16-m strip, 4 n-strips -> PT
        #pragma unroll
        for (int s = 0; s < 4; ++s) {
            float4 lv = *(const float4*)&Lb[nt + s * 16 + q * 4];
            floatx4 S = __builtin_amdgcn_mfma_f32_16x16x32_f16(
                fpre[s], gS, (floatx4){0.f, 0.f, 0.f, 0.f}, 0, 0, 0);
            half4 p;
            p[0] = (half_t)exp2f(fmaf(S[0], 1.44269504f, lv.x));
            p[1] = (half_t)exp2f(fmaf(S[1], 1.44269504f, lv.y));
            p[2] = (half_t)exp2f(fmaf(S[2], 1.44269504f, lv.z));
            p[3] = (half_t)exp2f(fmaf(S[3], 1.44269504f, lv.w));
            *(half4*)&PT[w * 16 + mc][s * 16 + q * 4] = p;
        }
        __syncthreads();              // B: PT/h_lds visible to all waves

        // ---- prefetch next tile (overlaps PV below; drained at next sync A)
        int ntn = nt + 64; if (ntn >= NN) ntn = 0;
        #pragma unroll
        for (int i = 0; i < 4; ++i)
            hpre[i] = *(const half8*)&hb[(size_t)(c0 + srow + 32 * i) * NN + ntn + sch * 8];
        #pragma unroll
        for (int s = 0; s < 4; ++s)
            fpre[s] = *(const half8*)&fTb[(size_t)(ntn + s * 16 + mc) * 32 + q * 8];

        // ---- PV: 4 k-chunks of 16; 2 MFMA32 each
        #pragma unroll
        for (int ch = 0; ch < 4; ++ch) {
            half8 Bf = *(const half8*)&PT[mb + l31][ch * 16 + l5 * 8];
            half8 A0 = *(const half8*)&h_lds[ca + l31][ch * 16 + l5 * 8];
            half8 A1 = *(const half8*)&h_lds[ca + 32 + l31][ch * 16 + l5 * 8];
            acc0 = __builtin_amdgcn_mfma_f32_32x32x16_f16(A0, Bf, acc0, 0, 0, 0);
            acc1 = __builtin_amdgcn_mfma_f32_32x32x16_f16(A1, Bf, acc1, 0, 0, 0);
        }
    }

    // ---- epilogue: out = src + gamma * acc  (D: col=l31, row=(r&3)+8*(r>>2)+4*l5)
    const float gm = gamma[0];
    const float* srcb = src + (size_t)b * CC * NN;
    float* outb = out + (size_t)b * CC * NN;
    const int m = m0 + mb + l31;
    #pragma unroll
    for (int r = 0; r < 16; ++r) {
        int crow = (r & 3) + 8 * (r >> 2) + 4 * l5;
        size_t i0 = (size_t)(c0 + ca + crow) * NN + m;
        outb[i0] = fmaf(gm, acc0[r], srcb[i0]);
        size_t i1 = (size_t)(c0 + ca + 32 + crow) * NN + m;
        outb[i1] = fmaf(gm, acc1[r], srcb[i1]);
    }
}

// ---------------------------------------------------------------------------
extern "C" void kernel_launch(void* const* d_in, const int* in_sizes, int n_in,
                              void* d_out, int out_size, void* d_ws, size_t ws_size,
                              hipStream_t stream)
{
    const float* x   = (const float*)d_in[0];
    const float* y   = (const float*)d_in[1];
    const float* Wfx = (const float*)d_in[2];
    const float* bfx = (const float*)d_in[3];
    const float* Wgx = (const float*)d_in[4];
    const float* bgx = (const float*)d_in[5];
    const float* Whx = (const float*)d_in[6];
    const float* bhx = (const float*)d_in[7];
    const float* Wfy = (const float*)d_in[8];
    const float* bfy = (const float*)d_in[9];
    const float* Wgy = (const float*)d_in[10];
    const float* bgy = (const float*)d_in[11];
    const float* Why = (const float*)d_in[12];
    const float* bhy = (const float*)d_in[13];
    const float* gam = (const float*)d_in[14];

    const size_t SZ_XT = (size_t)BB * NN * CC;   // 4,194,304 halves
    const size_t SZ_FG = (size_t)BB * NN * 32;   // 524,288 halves
    half_t* xTx   = (half_t*)d_ws;
    half_t* xTy   = xTx + SZ_XT;
    half_t* hx    = xTy + SZ_XT;
    half_t* hy    = hx + SZ_XT;
    half_t* fxT   = hy + SZ_XT;
    half_t* gxT   = fxT + SZ_FG;
    half_t* fyT   = gxT + SZ_FG;
    half_t* gyT   = fyT + SZ_FG;
    half_t* Wfx_h = gyT + SZ_FG;
    half_t* Wgx_h = Wfx_h + 32 * CC;
    half_t* Wfy_h = Wgx_h + 32 * CC;
    half_t* Wgy_h = Wfy_h + 32 * CC;
    half_t* Whx_h = Wgy_h + 32 * CC;
    half_t* Why_h = Whx_h + CC * CC;
    float*  Lx    = (float*)(Why_h + CC * CC);
    float*  Ly    = Lx + (size_t)BB * NN;

    float* outx = (float*)d_out;
    float* outy = outx + (size_t)BB * CC * NN;

    cvt_w_kernel<<<dim3(64, 6), 256, 0, stream>>>(Wfx, Wgx, Whx, Wfy, Wgy, Why,
                                                  Wfx_h, Wgx_h, Whx_h, Wfy_h, Wgy_h, Why_h);

    transpose_cvt_kernel<<<dim3(64, 4, 8), 256, 0, stream>>>(x, y, xTx, xTy);

    proj_fg_kernel<<<dim3(64, 4, 2), 256, 0, stream>>>(
        xTx, xTy, Wfx_h, Wgx_h, Wfy_h, Wgy_h, bfx, bgx, bfy, bgy, fxT, gxT, fyT, gyT);

    proj_h_kernel<<<dim3(64, 2, 8), 256, 0, stream>>>(
        xTx, xTy, Whx_h, Why_h, bhx, bhy, hx, hy);

    // att_x rows: fy vs gx -> Lx ; att_y rows: fx vs gy -> Ly
    stats_kernel<<<dim3(128, 4, 2), 256, 0, stream>>>(fyT, gxT, fxT, gyT, Lx, Ly);

    pv_kernel<<<dim3(64, 2, 8), 256, 0, stream>>>(
        fyT, gxT, hx, Lx, x, outx,
        fxT, gyT, hy, Ly, y, outy, gam);
}

// Round 7
// 308.906 us; speedup vs baseline: 9.2293x; 1.1046x over previous
//
#include <hip/hip_runtime.h>

// B=4, C=256, C8=32, N=4096. fp16 MFMA: 16x16x32 (S, proj), 32x32x16 (PV).
#define BB 4
#define CC 256
#define NN 4096

typedef _Float16 half_t;
typedef __attribute__((ext_vector_type(8))) _Float16 half8;
typedef __attribute__((ext_vector_type(4))) _Float16 half4;
typedef __attribute__((ext_vector_type(4))) float floatx4;
typedef __attribute__((ext_vector_type(16))) float floatx16;

// ---------------------------------------------------------------------------
// cvt_w: cast the six weight matrices to fp16. grid (64, 6).
// ---------------------------------------------------------------------------
__global__ __launch_bounds__(256)
void cvt_w_kernel(const float* __restrict__ Wfx, const float* __restrict__ Wgx,
                  const float* __restrict__ Whx, const float* __restrict__ Wfy,
                  const float* __restrict__ Wgy, const float* __restrict__ Why,
                  half_t* __restrict__ oWfx, half_t* __restrict__ oWgx,
                  half_t* __restrict__ oWhx, half_t* __restrict__ oWfy,
                  half_t* __restrict__ oWgy, half_t* __restrict__ oWhy)
{
    const float* src; half_t* dst; int n;
    switch (blockIdx.y) {
        case 0: src = Wfx; dst = oWfx; n = 32 * CC; break;
        case 1: src = Wgx; dst = oWgx; n = 32 * CC; break;
        case 2: src = Whx; dst = oWhx; n = CC * CC; break;
        case 3: src = Wfy; dst = oWfy; n = 32 * CC; break;
        case 4: src = Wgy; dst = oWgy; n = 32 * CC; break;
        default: src = Why; dst = oWhy; n = CC * CC; break;
    }
    int idx = (blockIdx.x * 256 + threadIdx.x) * 4;
    if (idx >= n) return;
    float4 v = *(const float4*)&src[idx];
    half4 h; h[0] = (half_t)v.x; h[1] = (half_t)v.y; h[2] = (half_t)v.z; h[3] = (half_t)v.w;
    *(half4*)&dst[idx] = h;
}

// ---------------------------------------------------------------------------
// transpose_cvt: xT[b][n][c] fp16 from in[b][c][n] fp32. grid (64, 4, 8).
// ---------------------------------------------------------------------------
__global__ __launch_bounds__(256)
void transpose_cvt_kernel(const float* __restrict__ x, const float* __restrict__ y,
                          half_t* __restrict__ xTx, half_t* __restrict__ xTy)
{
    const int n0 = blockIdx.x * 64;
    const int c0 = blockIdx.y * 64;
    const int b  = blockIdx.z & 3;
    const int sel = blockIdx.z >> 2;
    const float* in = sel ? y : x;
    half_t* outT = sel ? xTy : xTx;
    const int t  = threadIdx.x;
    const int ch = t & 7, nl = t >> 3;            // 8 c-chunks x 32 n
    const float* inb = in + (size_t)b * CC * NN;
    half_t* outb = outT + (size_t)b * NN * CC;

    #pragma unroll
    for (int p = 0; p < 2; ++p) {
        int n = n0 + nl + 32 * p;
        half8 hv;
        #pragma unroll
        for (int j = 0; j < 8; ++j)
            hv[j] = (half_t)inb[(size_t)(c0 + 8 * ch + j) * NN + n];
        *(half8*)&outb[(size_t)n * CC + c0 + 8 * ch] = hv;
    }
}

// ---------------------------------------------------------------------------
// proj_fg (MFMA): fT[n][32], gT[n][32]. grid (64, 4, 2): z = sel.
// ---------------------------------------------------------------------------
__global__ __launch_bounds__(256)
void proj_fg_kernel(const half_t* __restrict__ xTx, const half_t* __restrict__ xTy,
                    const half_t* __restrict__ Wfx, const half_t* __restrict__ Wgx,
                    const half_t* __restrict__ Wfy, const half_t* __restrict__ Wgy,
                    const float* __restrict__ bfx, const float* __restrict__ bgx,
                    const float* __restrict__ bfy, const float* __restrict__ bgy,
                    half_t* __restrict__ fxT, half_t* __restrict__ gxT,
                    half_t* __restrict__ fyT, half_t* __restrict__ gyT)
{
    const int n0 = blockIdx.x * 64;
    const int b  = blockIdx.y;
    const int sel = blockIdx.z;
    const half_t* xT = sel ? xTy : xTx;
    const half_t* Wf = sel ? Wfy : Wfx;
    const half_t* Wg = sel ? Wgy : Wgx;
    const float*  bf = sel ? bfy : bfx;
    const float*  bg = sel ? bgy : bgx;
    half_t* fT = sel ? fyT : fxT;
    half_t* gT = sel ? gyT : gxT;

    const int t  = threadIdx.x;
    const int w = t >> 6, lane = t & 63, q = lane >> 4, mc = lane & 15;
    const half_t* xTb = xT + (size_t)b * NN * CC;

    floatx4 acc[4];
    #pragma unroll
    for (int i = 0; i < 4; ++i) {
        float bv = (i < 2 ? bf : bg)[(i & 1) * 16 + mc];
        acc[i] = (floatx4){bv, bv, bv, bv};
    }

    #pragma unroll
    for (int ks = 0; ks < 8; ++ks) {
        int k0 = ks * 32 + q * 8;
        half8 af = *(const half8*)&xTb[(size_t)(n0 + w * 16 + mc) * CC + k0];
        #pragma unroll
        for (int i = 0; i < 4; ++i) {
            const half_t* Ws = (i < 2) ? Wf : Wg;
            half8 bfr = *(const half8*)&Ws[(size_t)((i & 1) * 16 + mc) * CC + k0];
            acc[i] = __builtin_amdgcn_mfma_f32_16x16x32_f16(af, bfr, acc[i], 0, 0, 0);
        }
    }

    #pragma unroll
    for (int i = 0; i < 4; ++i) {
        half_t* dst = (i < 2) ? fT : gT;
        #pragma unroll
        for (int r = 0; r < 4; ++r) {
            int n = n0 + w * 16 + q * 4 + r;
            dst[((size_t)b * NN + n) * 32 + (i & 1) * 16 + mc] = (half_t)acc[i][r];
        }
    }
}

// ---------------------------------------------------------------------------
// proj_h (MFMA): h[o][n] plain layout (R4-verified). grid (64, 2, 8).
// ---------------------------------------------------------------------------
__global__ __launch_bounds__(256)
void proj_h_kernel(const half_t* __restrict__ xTx, const half_t* __restrict__ xTy,
                   const half_t* __restrict__ Whx, const half_t* __restrict__ Why,
                   const float* __restrict__ bhx, const float* __restrict__ bhy,
                   half_t* __restrict__ hx, half_t* __restrict__ hy)
{
    const int n0 = blockIdx.x * 64;
    const int o0 = blockIdx.y * 128;
    const int b  = blockIdx.z & 3;
    const int sel = blockIdx.z >> 2;
    const half_t* xT = sel ? xTy : xTx;
    const half_t* Wh = sel ? Why : Whx;
    const float*  bh = sel ? bhy : bhx;
    half_t* h = sel ? hy : hx;

    const int t  = threadIdx.x;
    const int w = t >> 6, lane = t & 63, q = lane >> 4, mc = lane & 15;
    const half_t* xTb = xT + (size_t)b * NN * CC;
    half_t* hb = h + (size_t)b * CC * NN;

    floatx4 acc[2][4];
    #pragma unroll
    for (int j = 0; j < 2; ++j) {
        floatx4 bv;
        #pragma unroll
        for (int r = 0; r < 4; ++r) bv[r] = bh[o0 + w * 32 + j * 16 + q * 4 + r];
        #pragma unroll
        for (int i = 0; i < 4; ++i) acc[j][i] = bv;
    }

    #pragma unroll
    for (int ks = 0; ks < 8; ++ks) {
        int k0 = ks * 32 + q * 8;
        half8 a0 = *(const half8*)&Wh[(size_t)(o0 + w * 32 + mc) * CC + k0];
        half8 a1 = *(const half8*)&Wh[(size_t)(o0 + w * 32 + 16 + mc) * CC + k0];
        #pragma unroll
        for (int i = 0; i < 4; ++i) {
            half8 bfr = *(const half8*)&xTb[(size_t)(n0 + i * 16 + mc) * CC + k0];
            acc[0][i] = __builtin_amdgcn_mfma_f32_16x16x32_f16(a0, bfr, acc[0][i], 0, 0, 0);
            acc[1][i] = __builtin_amdgcn_mfma_f32_16x16x32_f16(a1, bfr, acc[1][i], 0, 0, 0);
        }
    }

    #pragma unroll
    for (int j = 0; j < 2; ++j)
        #pragma unroll
        for (int i = 0; i < 4; ++i)
            #pragma unroll
            for (int r = 0; r < 4; ++r) {
                int o = o0 + w * 32 + j * 16 + q * 4 + r;
                hb[(size_t)o * NN + n0 + i * 16 + mc] = (half_t)acc[j][i][r];
            }
}

// ---------------------------------------------------------------------------
// stats: Llog2[n] = -log2( sum_m exp(S[n,m]) ). grid (128, 4, 2).
// ---------------------------------------------------------------------------
__global__ __launch_bounds__(256)
void stats_kernel(const half_t* __restrict__ fT0, const half_t* __restrict__ gT0,
                  const half_t* __restrict__ fT1, const half_t* __restrict__ gT1,
                  float* __restrict__ L0, float* __restrict__ L1)
{
    __shared__ float red_l[4][32];
    const int b  = blockIdx.y;
    const int sel = blockIdx.z;
    const half_t* fT = sel ? fT1 : fT0;
    const half_t* gT = sel ? gT1 : gT0;
    float* Lout = sel ? L1 : L0;

    const int n0 = blockIdx.x * 32;
    const int t  = threadIdx.x;
    const int w = t >> 6, lane = t & 63, q = lane >> 4, mc = lane & 15;
    const half_t* fTb = fT + (size_t)b * NN * 32;
    const half_t* gTb = gT + (size_t)b * NN * 32;

    half8 a0 = *(const half8*)&fTb[(size_t)(n0 + mc) * 32 + q * 8];
    half8 a1 = *(const half8*)&fTb[(size_t)(n0 + 16 + mc) * 32 + q * 8];

    float l0[4] = {0.f, 0.f, 0.f, 0.f}, l1[4] = {0.f, 0.f, 0.f, 0.f};
    for (int it = 0; it < NN / 64; ++it) {
        int m = (it * 4 + w) * 16 + mc;
        half8 bfr = *(const half8*)&gTb[(size_t)m * 32 + q * 8];
        floatx4 S0 = __builtin_amdgcn_mfma_f32_16x16x32_f16(a0, bfr, (floatx4){0.f,0.f,0.f,0.f}, 0, 0, 0);
        floatx4 S1 = __builtin_amdgcn_mfma_f32_16x16x32_f16(a1, bfr, (floatx4){0.f,0.f,0.f,0.f}, 0, 0, 0);
        #pragma unroll
        for (int r = 0; r < 4; ++r) { l0[r] += __expf(S0[r]); l1[r] += __expf(S1[r]); }
    }
    #pragma unroll
    for (int r = 0; r < 4; ++r) {
        #pragma unroll
        for (int off = 1; off < 16; off <<= 1) {
            l0[r] += __shfl_xor(l0[r], off);
            l1[r] += __shfl_xor(l1[r], off);
        }
    }
    if (mc == 0)
        #pragma unroll
        for (int r = 0; r < 4; ++r) {
            red_l[w][q * 4 + r]      = l0[r];
            red_l[w][16 + q * 4 + r] = l1[r];
        }
    __syncthreads();
    if (t < 32) {
        float L = red_l[0][t] + red_l[1][t] + red_l[2][t] + red_l[3][t];
        Lout[(size_t)b * NN + n0 + t] = -log2f(L);
    }
}

// ---------------------------------------------------------------------------
// pv: out[c,m] = src[c,m] + gamma * sum_n h[c,n] * exp2(S*log2e + Llog2[n]).
// R4 structure with the m-tile doubled: grid (32, 2, 8), block tile
// 128c x 128m. Wave w: c-half ca=(w>>1)*64, m-half mb=(w&1)*64.
// S phase: wave computes PT rows w*32..w*32+31 (2 gS frags); PV: 32x32x16,
// acc[2][2] (2 c-strips x 2 m-strips). h staged via LDS (R4-proven path).
// ---------------------------------------------------------------------------
__global__ __launch_bounds__(256)
void pv_kernel(const half_t* __restrict__ fT0, const half_t* __restrict__ gT0,
               const half_t* __restrict__ h0, const float* __restrict__ L0,
               const float* __restrict__ src0, float* __restrict__ out0,
               const half_t* __restrict__ fT1, const half_t* __restrict__ gT1,
               const half_t* __restrict__ h1, const float* __restrict__ L1,
               const float* __restrict__ src1, float* __restrict__ out1,
               const float* __restrict__ gamma)
{
    __shared__ half_t h_lds[128][72];    // 18 KB, pitch 72 -> uniform quads
    __shared__ half_t PT[128][72];       // 18 KB, P^T[m][n]

    const int m0 = blockIdx.x * 128;
    const int c0 = blockIdx.y * 128;
    const int b  = blockIdx.z & 3;
    const int sel = blockIdx.z >> 2;
    const half_t* fT = sel ? fT1 : fT0;
    const half_t* gT = sel ? gT1 : gT0;
    const half_t* h  = sel ? h1 : h0;
    const float*  Lg = sel ? L1 : L0;
    const float*  src = sel ? src1 : src0;
    float* out = sel ? out1 : out0;

    const int t = threadIdx.x;
    const int w = t >> 6, lane = t & 63;
    const int q = lane >> 4, mc = lane & 15;
    const int l5 = lane >> 5, l31 = lane & 31;

    const half_t* fTb = fT + (size_t)b * NN * 32;
    const half_t* gTb = gT + (size_t)b * NN * 32;
    const half_t* hb  = h + (size_t)b * CC * NN;
    const float*  Lb  = Lg + (size_t)b * NN;

    // persistent S B-frags: m = m0 + w*32 + u*16 + mc
    half8 gS[2];
    gS[0] = *(const half8*)&gTb[(size_t)(m0 + w * 32 + mc) * 32 + q * 8];
    gS[1] = *(const half8*)&gTb[(size_t)(m0 + w * 32 + 16 + mc) * 32 + q * 8];

    // h stage addressing: thread covers rows srow+32i, chunk sch
    const int srow = t >> 3;    // 0..31
    const int sch  = t & 7;     // 0..7

    // prefetch tile 0
    half8 hpre[4], fpre[4];
    #pragma unroll
    for (int i = 0; i < 4; ++i)
        hpre[i] = *(const half8*)&hb[(size_t)(c0 + srow + 32 * i) * NN + sch * 8];
    #pragma unroll
    for (int s = 0; s < 4; ++s)
        fpre[s] = *(const half8*)&fTb[(size_t)(s * 16 + mc) * 32 + q * 8];

    floatx16 acc[2][2];                  // [c-strip a][m-strip bm]
    #pragma unroll
    for (int a = 0; a < 2; ++a)
        #pragma unroll
        for (int bm = 0; bm < 2; ++bm)
            #pragma unroll
            for (int r = 0; r < 16; ++r) acc[a][bm][r] = 0.f;

    const int ca = (w >> 1) * 64;     // PV c-base for this wave
    const int mb = (w & 1) * 64;      // PV m-base (local)

    for (int nt = 0; nt < NN; nt += 64) {
        __syncthreads();              // A: previous PV reads done
        #pragma unroll
        for (int i = 0; i < 4; ++i)
            *(half8*)&h_lds[srow + 32 * i][sch * 8] = hpre[i];

        // ---- S phase: this wave's 32-m strip (2x16), 4 n-strips -> PT
        #pragma unroll
        for (int s = 0; s < 4; ++s) {
            float4 lv = *(const float4*)&Lb[nt + s * 16 + q * 4];
            #pragma unroll
            for (int u = 0; u < 2; ++u) {
                floatx4 S = __builtin_amdgcn_mfma_f32_16x16x32_f16(
                    fpre[s], gS[u], (floatx4){0.f, 0.f, 0.f, 0.f}, 0, 0, 0);
                half4 p;
                p[0] = (half_t)exp2f(fmaf(S[0], 1.44269504f, lv.x));
                p[1] = (half_t)exp2f(fmaf(S[1], 1.44269504f, lv.y));
                p[2] = (half_t)exp2f(fmaf(S[2], 1.44269504f, lv.z));
                p[3] = (half_t)exp2f(fmaf(S[3], 1.44269504f, lv.w));
                *(half4*)&PT[w * 32 + u * 16 + mc][s * 16 + q * 4] = p;
            }
        }
        __syncthreads();              // B: PT/h_lds visible to all waves

        // ---- prefetch next tile (overlaps PV below)
        int ntn = nt + 64; if (ntn >= NN) ntn = 0;
        #pragma unroll
        for (int i = 0; i < 4; ++i)
            hpre[i] = *(const half8*)&hb[(size_t)(c0 + srow + 32 * i) * NN + ntn + sch * 8];
        #pragma unroll
        for (int s = 0; s < 4; ++s)
            fpre[s] = *(const half8*)&fTb[(size_t)(ntn + s * 16 + mc) * 32 + q * 8];

        // ---- PV: 4 k-chunks of 16; 4 MFMA32 each
        #pragma unroll
        for (int ch = 0; ch < 4; ++ch) {
            half8 B0 = *(const half8*)&PT[mb + l31][ch * 16 + l5 * 8];
            half8 B1 = *(const half8*)&PT[mb + 32 + l31][ch * 16 + l5 * 8];
            half8 A0 = *(const half8*)&h_lds[ca + l31][ch * 16 + l5 * 8];
            half8 A1 = *(const half8*)&h_lds[ca + 32 + l31][ch * 16 + l5 * 8];
            acc[0][0] = __builtin_amdgcn_mfma_f32_32x32x16_f16(A0, B0, acc[0][0], 0, 0, 0);
            acc[0][1] = __builtin_amdgcn_mfma_f32_32x32x16_f16(A0, B1, acc[0][1], 0, 0, 0);
            acc[1][0] = __builtin_amdgcn_mfma_f32_32x32x16_f16(A1, B0, acc[1][0], 0, 0, 0);
            acc[1][1] = __builtin_amdgcn_mfma_f32_32x32x16_f16(A1, B1, acc[1][1], 0, 0, 0);
        }
    }

    // ---- epilogue: out = src + gamma * acc (D: col=l31, row=(r&3)+8*(r>>2)+4*l5)
    const float gm = gamma[0];
    const float* srcb = src + (size_t)b * CC * NN;
    float* outb = out + (size_t)b * CC * NN;
    #pragma unroll
    for (int a = 0; a < 2; ++a)
        #pragma unroll
        for (int bm = 0; bm < 2; ++bm) {
            const int m = m0 + mb + bm * 32 + l31;
            #pragma unroll
            for (int r = 0; r < 16; ++r) {
                int c = c0 + ca + a * 32 + (r & 3) + 8 * (r >> 2) + 4 * l5;
                size_t idx = (size_t)c * NN + m;
                outb[idx] = fmaf(gm, acc[a][bm][r], srcb[idx]);
            }
        }
}

// ---------------------------------------------------------------------------
extern "C" void kernel_launch(void* const* d_in, const int* in_sizes, int n_in,
                              void* d_out, int out_size, void* d_ws, size_t ws_size,
                              hipStream_t stream)
{
    const float* x   = (const float*)d_in[0];
    const float* y   = (const float*)d_in[1];
    const float* Wfx = (const float*)d_in[2];
    const float* bfx = (const float*)d_in[3];
    const float* Wgx = (const float*)d_in[4];
    const float* bgx = (const float*)d_in[5];
    const float* Whx = (const float*)d_in[6];
    const float* bhx = (const float*)d_in[7];
    const float* Wfy = (const float*)d_in[8];
    const float* bfy = (const float*)d_in[9];
    const float* Wgy = (const float*)d_in[10];
    const float* bgy = (const float*)d_in[11];
    const float* Why = (const float*)d_in[12];
    const float* bhy = (const float*)d_in[13];
    const float* gam = (const float*)d_in[14];

    const size_t SZ_XT = (size_t)BB * NN * CC;   // 4,194,304 halves
    const size_t SZ_FG = (size_t)BB * NN * 32;   // 524,288 halves
    half_t* xTx   = (half_t*)d_ws;
    half_t* xTy   = xTx + SZ_XT;
    half_t* hx    = xTy + SZ_XT;
    half_t* hy    = hx + SZ_XT;
    half_t* fxT   = hy + SZ_XT;
    half_t* gxT   = fxT + SZ_FG;
    half_t* fyT   = gxT + SZ_FG;
    half_t* gyT   = fyT + SZ_FG;
    half_t* Wfx_h = gyT + SZ_FG;
    half_t* Wgx_h = Wfx_h + 32 * CC;
    half_t* Wfy_h = Wgx_h + 32 * CC;
    half_t* Wgy_h = Wfy_h + 32 * CC;
    half_t* Whx_h = Wgy_h + 32 * CC;
    half_t* Why_h = Whx_h + CC * CC;
    float*  Lx    = (float*)(Why_h + CC * CC);
    float*  Ly    = Lx + (size_t)BB * NN;

    float* outx = (float*)d_out;
    float* outy = outx + (size_t)BB * CC * NN;

    cvt_w_kernel<<<dim3(64, 6), 256, 0, stream>>>(Wfx, Wgx, Whx, Wfy, Wgy, Why,
                                                  Wfx_h, Wgx_h, Whx_h, Wfy_h, Wgy_h, Why_h);

    transpose_cvt_kernel<<<dim3(64, 4, 8), 256, 0, stream>>>(x, y, xTx, xTy);

    proj_fg_kernel<<<dim3(64, 4, 2), 256, 0, stream>>>(
        xTx, xTy, Wfx_h, Wgx_h, Wfy_h, Wgy_h, bfx, bgx, bfy, bgy, fxT, gxT, fyT, gyT);

    proj_h_kernel<<<dim3(64, 2, 8), 256, 0, stream>>>(
        xTx, xTy, Whx_h, Why_h, bhx, bhy, hx, hy);

    // att_x rows: fy vs gx -> Lx ; att_y rows: fx vs gy -> Ly
    stats_kernel<<<dim3(128, 4, 2), 256, 0, stream>>>(fyT, gxT, fxT, gyT, Lx, Ly);

    pv_kernel<<<dim3(32, 2, 8), 256, 0, stream>>>(
        fyT, gxT, hx, Lx, x, outx,
        fxT, gyT, hy, Ly, y, outy, gam);
}